// Round 2
// baseline (654.748 us; speedup 1.0000x reference)
//
#include <hip/hip_runtime.h>
#include <hip/hip_bf16.h>
#include <math.h>
#include <stdint.h>

// Problem constants
#define N_TOK   8192          // SL*BS
#define HS      1024
#define FFN     4096
#define NE      8
#define NA      16384         // N_TOK * TOPK
#define CAP     16384         // per-expert bucket capacity (worst case)
#define BM      256
#define MAXT    72            // max total M-tiles: 16384/256 + 8

typedef __attribute__((ext_vector_type(8))) short          bf16x8;
typedef __attribute__((ext_vector_type(4))) float          f32x4;
typedef __attribute__((ext_vector_type(4))) float          fvec4;
typedef __attribute__((ext_vector_type(4))) unsigned short usvec4;

__device__ __forceinline__ void gl_lds16(const void* g, void* l) {
  __builtin_amdgcn_global_load_lds(
      (const __attribute__((address_space(1))) unsigned int*)g,
      (__attribute__((address_space(3))) unsigned int*)l,
      16, 0, 0);
}

__device__ __forceinline__ unsigned short f2bf(float f) {
  union { float f; unsigned int u; } v; v.f = f;
  unsigned int r = v.u + 0x7FFFu + ((v.u >> 16) & 1u);
  return (unsigned short)(r >> 16);
}

// ---------------- conversion kernels ----------------

__global__ void cvt_x_kernel(const fvec4* __restrict__ in, unsigned short* __restrict__ out, int n4) {
  int i = blockIdx.x * 256 + threadIdx.x;
  if (i >= n4) return;
  fvec4 v = in[i];
  usvec4 o;
  o[0] = f2bf(v[0]); o[1] = f2bf(v[1]); o[2] = f2bf(v[2]); o[3] = f2bf(v[3]);
  *(usvec4*)(out + (size_t)i * 4) = o;
}

// in [E][R][C] f32 -> out [E][C][R] bf16 (K-contiguous B^T layout for GEMM)
__global__ void tpose_cvt_kernel(const float* __restrict__ in, unsigned short* __restrict__ out,
                                 int R, int C) {
  __shared__ float t[64][65];
  int bc = blockIdx.x * 64, br = blockIdx.y * 64, e = blockIdx.z;
  const float* ine = in + (size_t)e * R * C;
  unsigned short* oute = out + (size_t)e * R * C;
  int tx = threadIdx.x & 63, ty = threadIdx.x >> 6;   // ty in [0,4)
#pragma unroll
  for (int q = 0; q < 16; ++q) {
    int r = ty * 16 + q;
    t[r][tx] = ine[(size_t)(br + r) * C + bc + tx];
  }
  __syncthreads();
#pragma unroll
  for (int q = 0; q < 16; ++q) {
    int c = ty * 16 + q;
    oute[(size_t)(bc + c) * R + br + tx] = f2bf(t[tx][c]);
  }
}

// ---------------- routing ----------------

__global__ void route_kernel(const int* __restrict__ idx, const float* __restrict__ wts,
                             int* __restrict__ counts, int* __restrict__ btok,
                             int* __restrict__ bslot, float* __restrict__ bw) {
  int a = blockIdx.x * 256 + threadIdx.x;
  if (a >= NA) return;
  int e = idx[a];
  int pos = atomicAdd(&counts[e], 1);
  btok[(size_t)e * CAP + pos]  = a >> 1;     // token id
  bslot[(size_t)e * CAP + pos] = a;          // destination slot in perm buffer
  bw[(size_t)e * CAP + pos]    = wts[a];
}

__global__ void build_tiles_kernel(int* __restrict__ counts, int2* __restrict__ table) {
  if (threadIdx.x == 0 && blockIdx.x == 0) {
    int nt = 0;
    for (int e = 0; e < NE; ++e) {
      int c = counts[e];
      int t = (c + BM - 1) >> 8;
      for (int m = 0; m < t && nt < MAXT; ++m) table[nt++] = make_int2(e, m);
    }
    counts[8] = nt;
  }
}

// ---------------- grouped GEMM, counted-vmcnt triple-buffer pipeline ----------------
// Tile BM=256 x BN_=NWN*64, BK=32, 2*NWN waves, per-wave 128x64 output.
// LDS: 3 buffers of [A 256x32 | B BN_x32] bf16, XOR-swizzled (k_byte ^= ((row>>1)&3)<<4).
// Schedule per K-step: vmcnt(CPW) -> s_barrier -> stage kt+2 -> ds_read 12 frags
//                      -> lgkmcnt(0) -> setprio(1) -> 32 MFMA -> setprio(0).
template <int NWN, int EPI, int KDIM>
__global__ __launch_bounds__(NWN * 128, 2)
void moe_gemm(const unsigned short* __restrict__ Ab,   // xb (EPI=0) or h (EPI=1)
              const unsigned short* __restrict__ Bb,   // w1T / w2T, [E][N][K] bf16
              unsigned short* __restrict__ hout,       // EPI=0 output
              float* __restrict__ perm,                // EPI=1 output
              const int* __restrict__ btok,
              const int* __restrict__ bslot,
              const float* __restrict__ bw,
              const int* __restrict__ counts,
              const int2* __restrict__ table,
              int p0, int tc) {
  constexpr int NWAVES = 2 * NWN;
  constexpr int BN_ = NWN * 64;
  constexpr int NCH = 16 + BN_ / 16;       // 1KB staging chunks per K-tile
  constexpr int CPW = NCH / NWAVES;        // chunks (= gl_lds instrs) per wave per K-tile
  constexpr int BUFSZ = 16384 + BN_ * 64;  // bytes per buffer
  constexpr int NT = KDIM / 32;

  __shared__ char lds[3 * BUFSZ];

  int nt = counts[8];
  int j = blockIdx.y;
  if (j < p0 || j >= p0 + tc || j >= nt) return;
  int2 te = table[j];
  int e = te.x, tm = te.y;
  int count = counts[e];
  int bn0 = blockIdx.x * BN_;
  int slotb = j - p0;

  int tid = threadIdx.x;
  int wid = tid >> 6, lane = tid & 63;
  int wm = wid / NWN, wn = wid % NWN;

  const unsigned short* Be = Bb + (size_t)e * ((size_t)FFN * HS);

  // ---- staging setup (pre-swizzled global sources, wave-uniform LDS dests) ----
  const char* src[CPW];
  int dst[CPW];
#pragma unroll
  for (int q = 0; q < CPW; ++q) {
    int c = wid * CPW + q;
    int rr = (c < 16 ? c * 16 : (c - 16) * 16) + (lane >> 2);
    int klog = ((lane & 3) * 16) ^ (((rr >> 1) & 3) << 4);
    if (c < 16) {          // A chunk
      dst[q] = c * 1024;
      if (EPI == 0) {
        int grow = tm * BM + rr;
        int tok = (grow < count) ? btok[(size_t)e * CAP + grow] : 0;
        src[q] = (const char*)(Ab + (size_t)tok * KDIM) + klog;
      } else {
        src[q] = (const char*)(Ab + ((size_t)slotb * BM + rr) * KDIM) + klog;
      }
    } else {               // B chunk
      dst[q] = 16384 + (c - 16) * 1024;
      src[q] = (const char*)(Be + (size_t)(bn0 + rr) * KDIM) + klog;
    }
  }

  // ---- fragment read offsets (swizzled) ----
  int rA = wm * 128 + (lane & 15);
  int rB = wn * 64 + (lane & 15);
  int ks = (lane >> 4) * 16;
  int offA0 = rA * 64 + (ks ^ (((rA >> 1) & 3) << 4));
  int offB0 = 16384 + rB * 64 + (ks ^ (((rB >> 1) & 3) << 4));

  f32x4 acc[8][4] = {};

  // ---- prologue: stage kt0 -> buf0, kt1 -> buf1 ----
#pragma unroll
  for (int q = 0; q < CPW; ++q) gl_lds16(src[q], lds + dst[q]);
#pragma unroll
  for (int q = 0; q < CPW; ++q) gl_lds16(src[q] + 64, lds + BUFSZ + dst[q]);

  int bi = 0;
  for (int t = 0; t < NT; ++t) {
    // own kt-t loads landed (kt t+1's CPW may stay in flight)
    if constexpr (CPW == 4) asm volatile("s_waitcnt vmcnt(4)" ::: "memory");
    else                    asm volatile("s_waitcnt vmcnt(6)" ::: "memory");
    __builtin_amdgcn_sched_barrier(0);
    __builtin_amdgcn_s_barrier();   // all waves: kt t visible; buf (t+2)%3 free
    __builtin_amdgcn_sched_barrier(0);

    int kt2 = t + 2; if (kt2 >= NT) kt2 -= NT;   // wrap: harmless re-stage, keeps vmcnt uniform
    int bi2 = bi + 2; if (bi2 >= 3) bi2 -= 3;
    char* db = lds + bi2 * BUFSZ;
#pragma unroll
    for (int q = 0; q < CPW; ++q)
      gl_lds16(src[q] + (size_t)kt2 * 64, db + dst[q]);

    const char* rbuf = lds + bi * BUFSZ;
    bf16x8 a[8], b[4];
#pragma unroll
    for (int i = 0; i < 8; ++i) a[i] = *(const bf16x8*)(rbuf + offA0 + i * 1024);
#pragma unroll
    for (int n = 0; n < 4; ++n) b[n] = *(const bf16x8*)(rbuf + offB0 + n * 1024);
    asm volatile("s_waitcnt lgkmcnt(0)" ::: "memory");
    __builtin_amdgcn_sched_barrier(0);
    __builtin_amdgcn_s_setprio(1);
#pragma unroll
    for (int i = 0; i < 8; ++i)
#pragma unroll
      for (int n = 0; n < 4; ++n)
        acc[i][n] = __builtin_amdgcn_mfma_f32_16x16x32_bf16(a[i], b[n], acc[i][n], 0, 0, 0);
    __builtin_amdgcn_s_setprio(0);
    ++bi; if (bi >= 3) bi = 0;
  }

  // ---- epilogue ----
  if (EPI == 0) {
    size_t hb = (size_t)slotb * BM;
#pragma unroll
    for (int i = 0; i < 8; ++i) {
      int row = wm * 128 + i * 16 + ((lane >> 4) << 2);
#pragma unroll
      for (int n = 0; n < 4; ++n) {
        int col = bn0 + wn * 64 + n * 16 + (lane & 15);
#pragma unroll
        for (int r = 0; r < 4; ++r) {
          float v = acc[i][n][r];
          // gelu(v) = 0.5 v (1 + erf(v/sqrt2)), erf via A&S 7.1.26 (|err| < 1.5e-7)
          float aa = fabsf(v) * 0.70710678118654752f;
          float tt = 1.0f / (1.0f + 0.3275911f * aa);
          float p = ((((1.061405429f * tt - 1.453152027f) * tt + 1.421413741f) * tt
                      - 0.284496736f) * tt + 0.254829592f) * tt;
          float er = 1.0f - p * __expf(-aa * aa);
          float g = 0.5f * v * (v >= 0.f ? (1.0f + er) : (1.0f - er));
          hout[(hb + row + r) * FFN + col] = f2bf(g);
        }
      }
    }
  } else {
#pragma unroll
    for (int i = 0; i < 8; ++i) {
      int rowb = wm * 128 + i * 16 + ((lane >> 4) << 2);
#pragma unroll
      for (int r = 0; r < 4; ++r) {
        int grow = tm * BM + rowb + r;
        if (grow < count) {
          int s = bslot[(size_t)e * CAP + grow];
          float wgt = bw[(size_t)e * CAP + grow];
#pragma unroll
          for (int n = 0; n < 4; ++n) {
            int col = bn0 + wn * 64 + n * 16 + (lane & 15);
            perm[(size_t)s * HS + col] = wgt * acc[i][n][r];
          }
        }
      }
    }
  }
}

// ---------------- combine: out[t] = perm[2t] + perm[2t+1] ----------------
__global__ void combine_kernel(const fvec4* __restrict__ perm, fvec4* __restrict__ out, int n4) {
  int i = blockIdx.x * 256 + threadIdx.x;
  if (i >= n4) return;
  int t = i >> 8;            // HS/4 = 256 fvec4 per row
  int c = i & 255;
  out[i] = perm[(size_t)(2 * t) * 256 + c] + perm[(size_t)(2 * t + 1) * 256 + c];
}

// ---------------- host ----------------

extern "C" void kernel_launch(void* const* d_in, const int* in_sizes, int n_in,
                              void* d_out, int out_size, void* d_ws, size_t ws_size,
                              hipStream_t stream) {
  const float* x   = (const float*)d_in[0];
  const float* ew  = (const float*)d_in[1];
  // d_in[2] = scores (unused by reference output)
  const float* w1  = (const float*)d_in[3];
  const float* w2  = (const float*)d_in[4];
  const int*   eix = (const int*)d_in[5];

  char* ws = (char*)d_ws;
  const size_t o_w1T    = 0;                       // 67,108,864
  const size_t o_w2T    = 67108864ULL;             // 67,108,864
  const size_t o_xb     = 134217728ULL;            // 16,777,216
  const size_t o_btok   = 150994944ULL;            // 524,288
  const size_t o_bslot  = 151519232ULL;            // 524,288
  const size_t o_bw     = 152043520ULL;            // 524,288
  const size_t o_counts = 152567808ULL;            // 256
  const size_t o_table  = 152568064ULL;            // 1,280
  const size_t o_perm   = 152569344ULL;            // 67,108,864
  const size_t o_h      = 219678208ULL;            // up to 150,994,944

  unsigned short* w1T = (unsigned short*)(ws + o_w1T);
  unsigned short* w2T = (unsigned short*)(ws + o_w2T);
  unsigned short* xb  = (unsigned short*)(ws + o_xb);
  int*   btok   = (int*)(ws + o_btok);
  int*   bslot  = (int*)(ws + o_bslot);
  float* bw     = (float*)(ws + o_bw);
  int*   counts = (int*)(ws + o_counts);
  int2*  table  = (int2*)(ws + o_table);
  float* perm   = (float*)(ws + o_perm);
  unsigned short* hbuf = (unsigned short*)(ws + o_h);

  // h-buffer chunking if workspace is small
  long long havail = (long long)ws_size - (long long)o_h;
  long long tile_bytes = (long long)BM * FFN * 2;   // 2 MB per M-tile
  int tc = (int)(havail / tile_bytes);
  if (tc < 1) tc = 1;
  if (tc > MAXT) tc = MAXT;
  int npass = (MAXT + tc - 1) / tc;

  hipMemsetAsync(counts, 0, 256, stream);

  cvt_x_kernel<<<(N_TOK * HS / 4 + 255) / 256, 256, 0, stream>>>(
      (const fvec4*)x, xb, N_TOK * HS / 4);
  tpose_cvt_kernel<<<dim3(FFN / 64, HS / 64, NE), 256, 0, stream>>>(w1, w1T, HS, FFN);
  tpose_cvt_kernel<<<dim3(HS / 64, FFN / 64, NE), 256, 0, stream>>>(w2, w2T, FFN, HS);

  route_kernel<<<(NA + 255) / 256, 256, 0, stream>>>(eix, ew, counts, btok, bslot, bw);
  build_tiles_kernel<<<1, 64, 0, stream>>>(counts, table);

  for (int p = 0; p < npass; ++p) {
    // GEMM1: 256x256 tile, 8 waves, K=HS
    moe_gemm<4, 0, HS><<<dim3(FFN / 256, MAXT), 512, 0, stream>>>(
        xb, w1T, hbuf, perm, btok, bslot, bw, counts, table, p * tc, tc);
    // GEMM2: 256x128 tile, 4 waves, K=FFN (2 blocks/CU for the small-N shape)
    moe_gemm<2, 1, FFN><<<dim3(HS / 128, MAXT), 256, 0, stream>>>(
        hbuf, w2T, hbuf, perm, btok, bslot, bw, counts, table, p * tc, tc);
  }

  combine_kernel<<<(N_TOK * HS / 4 + 255) / 256, 256, 0, stream>>>(
      (const fvec4*)perm, (fvec4*)d_out, N_TOK * HS / 4);
}

// Round 3
// 608.441 us; speedup vs baseline: 1.0761x; 1.0761x over previous
//
#include <hip/hip_runtime.h>
#include <hip/hip_bf16.h>
#include <math.h>
#include <stdint.h>

// Problem constants
#define N_TOK   8192          // SL*BS
#define HS      1024
#define FFN     4096
#define NE      8
#define NA      16384         // N_TOK * TOPK
#define CAP     16384         // per-expert bucket capacity (worst case)
#define BM      256
#define MAXT    72            // max total M-tiles: 16384/256 + 8

typedef __attribute__((ext_vector_type(8))) short          bf16x8;
typedef __attribute__((ext_vector_type(4))) float          f32x4;
typedef __attribute__((ext_vector_type(4))) float          fvec4;
typedef __attribute__((ext_vector_type(4))) unsigned short usvec4;

__device__ __forceinline__ void gl_lds16(const void* g, void* l) {
  __builtin_amdgcn_global_load_lds(
      (const __attribute__((address_space(1))) unsigned int*)g,
      (__attribute__((address_space(3))) unsigned int*)l,
      16, 0, 0);
}

__device__ __forceinline__ unsigned short f2bf(float f) {
  union { float f; unsigned int u; } v; v.f = f;
  unsigned int r = v.u + 0x7FFFu + ((v.u >> 16) & 1u);
  return (unsigned short)(r >> 16);
}

// ---------------- conversion kernels ----------------

__global__ void cvt_x_kernel(const fvec4* __restrict__ in, unsigned short* __restrict__ out, int n4) {
  int i = blockIdx.x * 256 + threadIdx.x;
  if (i >= n4) return;
  fvec4 v = in[i];
  usvec4 o;
  o[0] = f2bf(v[0]); o[1] = f2bf(v[1]); o[2] = f2bf(v[2]); o[3] = f2bf(v[3]);
  *(usvec4*)(out + (size_t)i * 4) = o;
}

// in [E][R][C] f32 -> out [E][C][R] bf16 (K-contiguous B^T layout for GEMM)
__global__ void tpose_cvt_kernel(const float* __restrict__ in, unsigned short* __restrict__ out,
                                 int R, int C) {
  __shared__ float t[64][65];
  int bc = blockIdx.x * 64, br = blockIdx.y * 64, e = blockIdx.z;
  const float* ine = in + (size_t)e * R * C;
  unsigned short* oute = out + (size_t)e * R * C;
  int tx = threadIdx.x & 63, ty = threadIdx.x >> 6;   // ty in [0,4)
#pragma unroll
  for (int q = 0; q < 16; ++q) {
    int r = ty * 16 + q;
    t[r][tx] = ine[(size_t)(br + r) * C + bc + tx];
  }
  __syncthreads();
#pragma unroll
  for (int q = 0; q < 16; ++q) {
    int c = ty * 16 + q;
    oute[(size_t)(bc + c) * R + br + tx] = f2bf(t[tx][c]);
  }
}

// ---------------- routing ----------------

__global__ void route_kernel(const int* __restrict__ idx, const float* __restrict__ wts,
                             int* __restrict__ counts, int* __restrict__ btok,
                             int* __restrict__ bslot, float* __restrict__ bw) {
  int a = blockIdx.x * 256 + threadIdx.x;
  if (a >= NA) return;
  int e = idx[a];
  int pos = atomicAdd(&counts[e], 1);
  btok[(size_t)e * CAP + pos]  = a >> 1;     // token id
  bslot[(size_t)e * CAP + pos] = a;          // destination slot in perm buffer
  bw[(size_t)e * CAP + pos]    = wts[a];
}

__global__ void build_tiles_kernel(int* __restrict__ counts, int2* __restrict__ table) {
  if (threadIdx.x == 0 && blockIdx.x == 0) {
    int nt = 0;
    for (int e = 0; e < NE; ++e) {
      int c = counts[e];
      int t = (c + BM - 1) >> 8;
      for (int m = 0; m < t && nt < MAXT; ++m) table[nt++] = make_int2(e, m);
    }
    counts[8] = nt;
  }
}

// ---------------- grouped GEMM, counted-vmcnt triple-buffer pipeline ----------------
// Tile BM=256 x BN_=NWN*64, BK=32, 2*NWN waves, per-wave 128x64 output.
// LDS: 3 buffers of [A 256x32 | B BN_x32] bf16, XOR-swizzled (k_byte ^= ((row>>1)&3)<<4).
// Inner loop: reads issued in 4 pinned groups interleaved with 4x8-MFMA groups on
// disjoint accumulators; compiler inserts counted lgkm waits -> LDS/MFMA pipelined.
// XCD-clustered grid: all N-blocks of one M-tile contiguous on one XCD.
template <int NWN, int EPI, int KDIM, int NOUT>
__global__ __launch_bounds__(NWN * 128, 2)
void moe_gemm(const unsigned short* __restrict__ Ab,   // xb (EPI=0) or h (EPI=1)
              const unsigned short* __restrict__ Bb,   // w1T / w2T, [E][N][K] bf16
              unsigned short* __restrict__ hout,       // EPI=0 output
              float* __restrict__ perm,                // EPI=1 output
              const int* __restrict__ btok,
              const int* __restrict__ bslot,
              const float* __restrict__ bw,
              const int* __restrict__ counts,
              const int2* __restrict__ table,
              int p0, int tc) {
  constexpr int NWAVES = 2 * NWN;
  constexpr int BN_ = NWN * 64;
  constexpr int NBLK = NOUT / BN_;         // N-blocks per tile (8 or 16, pow2)
  constexpr int NCH = 16 + BN_ / 16;       // 1KB staging chunks per K-tile
  constexpr int CPW = NCH / NWAVES;        // gl_lds instrs per wave per K-tile
  constexpr int BUFSZ = 16384 + BN_ * 64;  // bytes per buffer
  constexpr int NT = KDIM / 32;

  __shared__ char lds[3 * BUFSZ];

  // XCD-clustered decode: xcd = bid&7; tiles round-robin over XCDs; all NBLK
  // n-blocks of a tile are consecutive slots on one XCD (A-panel L2 reuse).
  int bid = blockIdx.x;
  int xcd = bid & 7, slot = bid >> 3;
  int j = xcd + 8 * (slot / NBLK);
  int bn0 = (slot % NBLK) * BN_;

  int nt = counts[8];
  if (j < p0 || j >= p0 + tc || j >= nt) return;
  int2 te = table[j];
  int e = te.x, tm = te.y;
  int count = counts[e];
  int slotb = j - p0;

  int tid = threadIdx.x;
  int wid = tid >> 6, lane = tid & 63;
  int wm = wid / NWN, wn = wid % NWN;

  const unsigned short* Be = Bb + (size_t)e * ((size_t)FFN * HS);

  // ---- staging setup (pre-swizzled global sources, wave-uniform LDS dests) ----
  const char* src[CPW];
  int dst[CPW];
#pragma unroll
  for (int q = 0; q < CPW; ++q) {
    int c = wid * CPW + q;
    int rr = (c < 16 ? c * 16 : (c - 16) * 16) + (lane >> 2);
    int klog = ((lane & 3) * 16) ^ (((rr >> 1) & 3) << 4);
    if (c < 16) {          // A chunk
      dst[q] = c * 1024;
      if (EPI == 0) {
        int grow = tm * BM + rr;
        int tok = (grow < count) ? btok[(size_t)e * CAP + grow] : 0;
        src[q] = (const char*)(Ab + (size_t)tok * KDIM) + klog;
      } else {
        src[q] = (const char*)(Ab + ((size_t)slotb * BM + rr) * KDIM) + klog;
      }
    } else {               // B chunk
      dst[q] = 16384 + (c - 16) * 1024;
      src[q] = (const char*)(Be + (size_t)(bn0 + rr) * KDIM) + klog;
    }
  }

  // ---- fragment read offsets (swizzled) ----
  int rA = wm * 128 + (lane & 15);
  int rB = wn * 64 + (lane & 15);
  int ks = (lane >> 4) * 16;
  int offA0 = rA * 64 + (ks ^ (((rA >> 1) & 3) << 4));
  int offB0 = 16384 + rB * 64 + (ks ^ (((rB >> 1) & 3) << 4));

  f32x4 acc[8][4] = {};

  // ---- prologue: stage kt0 -> buf0, kt1 -> buf1 ----
#pragma unroll
  for (int q = 0; q < CPW; ++q) gl_lds16(src[q], lds + dst[q]);
#pragma unroll
  for (int q = 0; q < CPW; ++q) gl_lds16(src[q] + 64, lds + BUFSZ + dst[q]);

  int bi = 0;
  for (int t = 0; t < NT; ++t) {
    // own kt-t loads landed (kt t+1's CPW may stay in flight)
    if constexpr (CPW == 4) asm volatile("s_waitcnt vmcnt(4)" ::: "memory");
    else                    asm volatile("s_waitcnt vmcnt(6)" ::: "memory");
    __builtin_amdgcn_sched_barrier(0);
    __builtin_amdgcn_s_barrier();   // all waves: kt t visible; buf (t+2)%3 free
    __builtin_amdgcn_sched_barrier(0);

    int kt2 = t + 2; if (kt2 >= NT) kt2 -= NT;   // wrap: harmless re-stage, keeps vmcnt uniform
    int bi2 = bi + 2; if (bi2 >= 3) bi2 -= 3;
    char* db = lds + bi2 * BUFSZ;
#pragma unroll
    for (int q = 0; q < CPW; ++q)
      gl_lds16(src[q] + (size_t)kt2 * 64, db + dst[q]);

    const char* rbuf = lds + bi * BUFSZ;
    bf16x8 a[8], b[4];
    // read group 0: all B frags + a0,a1
    b[0] = *(const bf16x8*)(rbuf + offB0);
    b[1] = *(const bf16x8*)(rbuf + offB0 + 1024);
    b[2] = *(const bf16x8*)(rbuf + offB0 + 2048);
    b[3] = *(const bf16x8*)(rbuf + offB0 + 3072);
    a[0] = *(const bf16x8*)(rbuf + offA0);
    a[1] = *(const bf16x8*)(rbuf + offA0 + 1024);
    __builtin_amdgcn_sched_barrier(0);
    a[2] = *(const bf16x8*)(rbuf + offA0 + 2048);
    a[3] = *(const bf16x8*)(rbuf + offA0 + 3072);
    __builtin_amdgcn_sched_barrier(0);
    a[4] = *(const bf16x8*)(rbuf + offA0 + 4096);
    a[5] = *(const bf16x8*)(rbuf + offA0 + 5120);
    __builtin_amdgcn_sched_barrier(0);
    a[6] = *(const bf16x8*)(rbuf + offA0 + 6144);
    a[7] = *(const bf16x8*)(rbuf + offA0 + 7168);
    __builtin_amdgcn_sched_barrier(0);
    // MFMA groups on disjoint accumulators; compiler emits counted lgkm waits
    __builtin_amdgcn_s_setprio(1);
#pragma unroll
    for (int g = 0; g < 4; ++g) {
#pragma unroll
      for (int i = 2 * g; i < 2 * g + 2; ++i)
#pragma unroll
        for (int n = 0; n < 4; ++n)
          acc[i][n] = __builtin_amdgcn_mfma_f32_16x16x32_bf16(a[i], b[n], acc[i][n], 0, 0, 0);
      __builtin_amdgcn_sched_barrier(0);
    }
    __builtin_amdgcn_s_setprio(0);
    ++bi; if (bi >= 3) bi = 0;
  }

  // ---- epilogue ----
  if (EPI == 0) {
    size_t hb = (size_t)slotb * BM;
#pragma unroll
    for (int i = 0; i < 8; ++i) {
      int row = wm * 128 + i * 16 + ((lane >> 4) << 2);
#pragma unroll
      for (int n = 0; n < 4; ++n) {
        int col = bn0 + wn * 64 + n * 16 + (lane & 15);
#pragma unroll
        for (int r = 0; r < 4; ++r) {
          float v = acc[i][n][r];
          // gelu(v) = v * sigmoid(2u), u = 0.79788456 v (1 + 0.044715 v^2)
          float x2 = v * v;
          float u2 = 1.5957691216057308f * v * fmaf(0.044715f, x2, 1.0f);  // 2u
          u2 = fminf(fmaxf(u2, -30.f), 30.f);
          float ee = __expf(u2);
          float g = v * __fdividef(ee, ee + 1.0f);
          hout[(hb + row + r) * FFN + col] = f2bf(g);
        }
      }
    }
  } else {
#pragma unroll
    for (int i = 0; i < 8; ++i) {
      int rowb = wm * 128 + i * 16 + ((lane >> 4) << 2);
#pragma unroll
      for (int r = 0; r < 4; ++r) {
        int grow = tm * BM + rowb + r;
        if (grow < count) {
          int s = bslot[(size_t)e * CAP + grow];
          float wgt = bw[(size_t)e * CAP + grow];
#pragma unroll
          for (int n = 0; n < 4; ++n) {
            int col = bn0 + wn * 64 + n * 16 + (lane & 15);
            perm[(size_t)s * HS + col] = wgt * acc[i][n][r];
          }
        }
      }
    }
  }
}

// ---------------- combine: out[t] = perm[2t] + perm[2t+1] ----------------
__global__ void combine_kernel(const fvec4* __restrict__ perm, fvec4* __restrict__ out, int n4) {
  int i = blockIdx.x * 256 + threadIdx.x;
  if (i >= n4) return;
  int t = i >> 8;            // HS/4 = 256 fvec4 per row
  int c = i & 255;
  out[i] = perm[(size_t)(2 * t) * 256 + c] + perm[(size_t)(2 * t + 1) * 256 + c];
}

// ---------------- host ----------------

extern "C" void kernel_launch(void* const* d_in, const int* in_sizes, int n_in,
                              void* d_out, int out_size, void* d_ws, size_t ws_size,
                              hipStream_t stream) {
  const float* x   = (const float*)d_in[0];
  const float* ew  = (const float*)d_in[1];
  // d_in[2] = scores (unused by reference output)
  const float* w1  = (const float*)d_in[3];
  const float* w2  = (const float*)d_in[4];
  const int*   eix = (const int*)d_in[5];

  char* ws = (char*)d_ws;
  const size_t o_w1T    = 0;                       // 67,108,864
  const size_t o_w2T    = 67108864ULL;             // 67,108,864
  const size_t o_xb     = 134217728ULL;            // 16,777,216
  const size_t o_btok   = 150994944ULL;            // 524,288
  const size_t o_bslot  = 151519232ULL;            // 524,288
  const size_t o_bw     = 152043520ULL;            // 524,288
  const size_t o_counts = 152567808ULL;            // 256
  const size_t o_table  = 152568064ULL;            // 1,280
  const size_t o_perm   = 152569344ULL;            // 67,108,864
  const size_t o_h      = 219678208ULL;            // up to 150,994,944

  unsigned short* w1T = (unsigned short*)(ws + o_w1T);
  unsigned short* w2T = (unsigned short*)(ws + o_w2T);
  unsigned short* xb  = (unsigned short*)(ws + o_xb);
  int*   btok   = (int*)(ws + o_btok);
  int*   bslot  = (int*)(ws + o_bslot);
  float* bw     = (float*)(ws + o_bw);
  int*   counts = (int*)(ws + o_counts);
  int2*  table  = (int2*)(ws + o_table);
  float* perm   = (float*)(ws + o_perm);
  unsigned short* hbuf = (unsigned short*)(ws + o_h);

  // h-buffer chunking if workspace is small
  long long havail = (long long)ws_size - (long long)o_h;
  long long tile_bytes = (long long)BM * FFN * 2;   // 2 MB per M-tile
  int tc = (int)(havail / tile_bytes);
  if (tc < 1) tc = 1;
  if (tc > MAXT) tc = MAXT;
  int npass = (MAXT + tc - 1) / tc;

  hipMemsetAsync(counts, 0, 256, stream);

  cvt_x_kernel<<<(N_TOK * HS / 4 + 255) / 256, 256, 0, stream>>>(
      (const fvec4*)x, xb, N_TOK * HS / 4);
  tpose_cvt_kernel<<<dim3(FFN / 64, HS / 64, NE), 256, 0, stream>>>(w1, w1T, HS, FFN);
  tpose_cvt_kernel<<<dim3(HS / 64, FFN / 64, NE), 256, 0, stream>>>(w2, w2T, FFN, HS);

  route_kernel<<<(NA + 255) / 256, 256, 0, stream>>>(eix, ew, counts, btok, bslot, bw);
  build_tiles_kernel<<<1, 64, 0, stream>>>(counts, table);

  for (int p = 0; p < npass; ++p) {
    // GEMM1: 256x256 tile, 8 waves, K=HS, N=FFN -> 16 N-blocks * 72 tiles = 1152
    moe_gemm<4, 0, HS, FFN><<<dim3(MAXT * 16), 512, 0, stream>>>(
        xb, w1T, hbuf, perm, btok, bslot, bw, counts, table, p * tc, tc);
    // GEMM2: 256x128 tile, 4 waves, K=FFN, N=HS -> 8 N-blocks * 72 tiles = 576
    moe_gemm<2, 1, FFN, HS><<<dim3(MAXT * 8), 256, 0, stream>>>(
        hbuf, w2T, hbuf, perm, btok, bslot, bw, counts, table, p * tc, tc);
  }

  combine_kernel<<<(N_TOK * HS / 4 + 255) / 256, 256, 0, stream>>>(
      (const fvec4*)perm, (fvec4*)d_out, N_TOK * HS / 4);
}